// Round 2
// baseline (807.863 us; speedup 1.0000x reference)
//
#include <hip/hip_runtime.h>

#define N_NODES 100000
#define N_EDGES 1600000
#define STATE 4
#define OUT_C 16
#define HID 5
#define MAX_IT 10
#define ARC_D 17   // 1 + 2*FEAT

// branch-free tanh: 1 - 2/(exp(2x)+1); saturates to +-1, NaN-free for finite x
__device__ __forceinline__ float fast_tanh(float x) {
    float e = __expf(2.0f * x);
    return 1.0f - 2.0f / (e + 1.0f);
}

// ---------------- histogram of parents ----------------
__global__ void hist_kernel(const int* __restrict__ parent, int* __restrict__ counts, int E) {
    int e = blockIdx.x * blockDim.x + threadIdx.x;
    if (e < E) atomicAdd(&counts[parent[e]], 1);
}

// ---------------- exclusive scan (3-phase) ----------------
#define SCAN_B 1024
__global__ __launch_bounds__(SCAN_B) void scanA(const int* __restrict__ counts,
                                                int* __restrict__ off,
                                                int* __restrict__ bsum, int n) {
    __shared__ int lds[SCAN_B];
    int t = threadIdx.x;
    int i = blockIdx.x * SCAN_B + t;
    int v = (i < n - 1) ? counts[i] : 0;   // phantom last element = 0 -> off[N]=E
    lds[t] = v;
    for (int s = 1; s < SCAN_B; s <<= 1) {
        __syncthreads();
        int u = (t >= s) ? lds[t - s] : 0;
        __syncthreads();
        lds[t] += u;
    }
    __syncthreads();
    if (i < n) off[i] = lds[t] - v;              // exclusive, pre-base
    if (t == SCAN_B - 1) bsum[blockIdx.x] = lds[t];
}

// parallel exclusive scan of up to 128 block sums (nb<=128 here: 98 blocks)
__global__ __launch_bounds__(128) void scanB(int* __restrict__ bsum, int nb) {
    __shared__ int lds[128];
    int t = threadIdx.x;
    int v = (t < nb) ? bsum[t] : 0;
    lds[t] = v;
    for (int s = 1; s < 128; s <<= 1) {
        __syncthreads();
        int u = (t >= s) ? lds[t - s] : 0;
        __syncthreads();
        lds[t] += u;
    }
    __syncthreads();
    if (t < nb) bsum[t] = lds[t] - v;            // exclusive
}

__global__ __launch_bounds__(SCAN_B) void scanC(int* __restrict__ off, const int* __restrict__ bsum,
                                                int* __restrict__ cursor, int n) {
    int i = blockIdx.x * SCAN_B + threadIdx.x;
    if (i < n) {
        int v = off[i] + bsum[blockIdx.x];
        off[i] = v;
        if (i < n - 1) cursor[i] = v;            // cursor[node] = segment start
    }
}

// ---------------- build: pre1 = arc_feat @ W1[0:17] + b1, permuted to CSR order ----------------
#define BBLK 256
__global__ __launch_bounds__(BBLK) void build_kernel(const float* __restrict__ arc,
                                                     const float* __restrict__ W1,
                                                     const float* __restrict__ b1,
                                                     const int* __restrict__ parent,
                                                     const int* __restrict__ child,
                                                     int* __restrict__ cursor,
                                                     float* __restrict__ pre1,
                                                     int* __restrict__ childp, int E) {
    __shared__ float lds[BBLK * ARC_D];
    int t = threadIdx.x;
    int base = blockIdx.x * BBLK;
    int cnt = E - base; if (cnt > BBLK) cnt = BBLK;
    // coalesced stage of 256 rows x 17 floats
    for (int k = t; k < cnt * ARC_D; k += BBLK)
        lds[k] = arc[(size_t)base * ARC_D + k];
    __syncthreads();
    if (t < cnt) {
        int e = base + t;
        const float* row = &lds[t * ARC_D];
        float p[HID];
        #pragma unroll
        for (int j = 0; j < HID; ++j) p[j] = b1[j];
        #pragma unroll
        for (int i = 0; i < ARC_D; ++i) {
            float x = row[i];
            #pragma unroll
            for (int j = 0; j < HID; ++j) p[j] += x * W1[i * HID + j];
        }
        int pa = parent[e];
        int pos = atomicAdd(&cursor[pa], 1);
        #pragma unroll
        for (int j = 0; j < HID; ++j) pre1[(size_t)pos * HID + j] = p[j];
        childp[pos] = child[e];
    }
}

// ---------------- one fixed-point iteration (node-parallel, atomic-free) ----------------
__global__ __launch_bounds__(256) void iter_kernel(const int* __restrict__ off,
                                                   const int* __restrict__ childp,
                                                   const float* __restrict__ pre1,
                                                   const float* __restrict__ W1,
                                                   const float* __restrict__ W2,
                                                   const float* __restrict__ b2,
                                                   const float* __restrict__ src,
                                                   float* __restrict__ dst) {
    int n = blockIdx.x * blockDim.x + threadIdx.x;
    if (n >= N_NODES) return;
    // uniform-address weight loads -> scalar regs
    float w1b[STATE][HID];
    #pragma unroll
    for (int k = 0; k < STATE; ++k)
        #pragma unroll
        for (int j = 0; j < HID; ++j) w1b[k][j] = W1[(ARC_D + k) * HID + j];
    float w2[HID][STATE];
    #pragma unroll
    for (int j = 0; j < HID; ++j)
        #pragma unroll
        for (int k = 0; k < STATE; ++k) w2[j][k] = W2[j * STATE + k];
    float b2v[STATE];
    #pragma unroll
    for (int k = 0; k < STATE; ++k) b2v[k] = b2[k];

    int s0 = off[n];
    int s1 = off[n + 1];
    float acc0 = 0.f, acc1 = 0.f, acc2 = 0.f, acc3 = 0.f;
    for (int i = s0; i < s1; ++i) {
        int c = childp[i];
        float4 s = ((const float4*)src)[c];
        float h[HID];
        #pragma unroll
        for (int j = 0; j < HID; ++j) {
            float v = pre1[(size_t)i * HID + j]
                    + s.x * w1b[0][j] + s.y * w1b[1][j]
                    + s.z * w1b[2][j] + s.w * w1b[3][j];
            h[j] = fast_tanh(v);
        }
        float m[STATE];
        #pragma unroll
        for (int k = 0; k < STATE; ++k) {
            float v = b2v[k];
            #pragma unroll
            for (int j = 0; j < HID; ++j) v += h[j] * w2[j][k];
            m[k] = fast_tanh(v);
        }
        acc0 += m[0]; acc1 += m[1]; acc2 += m[2]; acc3 += m[3];
    }
    ((float4*)dst)[n] = make_float4(acc0, acc1, acc2, acc3);
}

// ---------------- output MLP + softmax ----------------
__global__ __launch_bounds__(256) void out_kernel(const float* __restrict__ state,
                                                  const float* __restrict__ Wo1,
                                                  const float* __restrict__ bo1,
                                                  const float* __restrict__ Wo2,
                                                  const float* __restrict__ bo2,
                                                  float* __restrict__ out) {
    int n = blockIdx.x * blockDim.x + threadIdx.x;
    if (n >= N_NODES) return;
    float4 s = ((const float4*)state)[n];
    float ho[HID];
    #pragma unroll
    for (int j = 0; j < HID; ++j) {
        float v = bo1[j] + s.x * Wo1[0 * HID + j] + s.y * Wo1[1 * HID + j]
                         + s.z * Wo1[2 * HID + j] + s.w * Wo1[3 * HID + j];
        ho[j] = fast_tanh(v);
    }
    float lg[OUT_C];
    float mx = -1e30f;
    #pragma unroll
    for (int o = 0; o < OUT_C; ++o) {
        float v = bo2[o];
        #pragma unroll
        for (int j = 0; j < HID; ++j) v += ho[j] * Wo2[j * OUT_C + o];
        lg[o] = v; mx = fmaxf(mx, v);
    }
    float sum = 0.f;
    #pragma unroll
    for (int o = 0; o < OUT_C; ++o) { lg[o] = __expf(lg[o] - mx); sum += lg[o]; }
    float inv = 1.0f / sum;
    float4* op = (float4*)&out[(size_t)n * OUT_C];
    op[0] = make_float4(lg[0] * inv, lg[1] * inv, lg[2] * inv, lg[3] * inv);
    op[1] = make_float4(lg[4] * inv, lg[5] * inv, lg[6] * inv, lg[7] * inv);
    op[2] = make_float4(lg[8] * inv, lg[9] * inv, lg[10] * inv, lg[11] * inv);
    op[3] = make_float4(lg[12] * inv, lg[13] * inv, lg[14] * inv, lg[15] * inv);
}

extern "C" void kernel_launch(void* const* d_in, const int* in_sizes, int n_in,
                              void* d_out, int out_size, void* d_ws, size_t ws_size,
                              hipStream_t stream) {
    const float* arc   = (const float*)d_in[0];
    const float* W1    = (const float*)d_in[1];
    const float* b1    = (const float*)d_in[2];
    const float* W2    = (const float*)d_in[3];
    const float* b2    = (const float*)d_in[4];
    const float* Wo1   = (const float*)d_in[5];
    const float* bo1   = (const float*)d_in[6];
    const float* Wo2   = (const float*)d_in[7];
    const float* bo2   = (const float*)d_in[8];
    const int* parent  = (const int*)d_in[9];
    const int* child   = (const int*)d_in[10];
    float* out = (float*)d_out;

    char* ws = (char*)d_ws;
    size_t o = 0;
    auto alloc = [&](size_t bytes) { void* p = ws + o; o += (bytes + 255) & ~255ULL; return p; };
    float* pre1   = (float*)alloc((size_t)N_EDGES * HID * 4);   // 32 MB, CSR-ordered
    int*   childp = (int*)alloc((size_t)N_EDGES * 4);           // 6.4 MB
    int*   counts = (int*)alloc((size_t)N_NODES * 4);
    int*   off    = (int*)alloc((size_t)(N_NODES + 1) * 4);
    int*   cursor = (int*)alloc((size_t)N_NODES * 4);
    int*   bsum   = (int*)alloc(1024 * 4);
    float* stateA = (float*)alloc((size_t)N_NODES * STATE * 4);
    float* stateB = (float*)alloc((size_t)N_NODES * STATE * 4);

    hipMemsetAsync(counts, 0, (size_t)N_NODES * 4, stream);
    hipMemsetAsync(stateA, 0, (size_t)N_NODES * STATE * 4, stream);  // state0 = zeros

    hist_kernel<<<(N_EDGES + 255) / 256, 256, 0, stream>>>(parent, counts, N_EDGES);
    int n = N_NODES + 1;
    int nb = (n + SCAN_B - 1) / SCAN_B;     // 98
    scanA<<<nb, SCAN_B, 0, stream>>>(counts, off, bsum, n);
    scanB<<<1, 128, 0, stream>>>(bsum, nb);
    scanC<<<nb, SCAN_B, 0, stream>>>(off, bsum, cursor, n);
    build_kernel<<<(N_EDGES + BBLK - 1) / BBLK, BBLK, 0, stream>>>(arc, W1, b1, parent, child,
                                                                   cursor, pre1, childp, N_EDGES);
    float* src = stateA; float* dst = stateB;
    for (int it = 0; it < MAX_IT; ++it) {
        iter_kernel<<<(N_NODES + 255) / 256, 256, 0, stream>>>(off, childp, pre1, W1, W2, b2, src, dst);
        float* tmp = src; src = dst; dst = tmp;
    }
    out_kernel<<<(N_NODES + 255) / 256, 256, 0, stream>>>(src, Wo1, bo1, Wo2, bo2, out);
}

// Round 4
// 606.014 us; speedup vs baseline: 1.3331x; 1.3331x over previous
//
#include <hip/hip_runtime.h>

#define N_NODES 100000
#define N_EDGES 1600000
#define STATE 4
#define OUT_C 16
#define HID 5
#define MAX_IT 10
#define ARC_D 17   // 1 + 2*FEAT

// branch-free tanh: 1 - 2/(exp(2x)+1); saturates to +-1, NaN-free for finite x
__device__ __forceinline__ float fast_tanh(float x) {
    float e = __expf(2.0f * x);
    return 1.0f - 2.0f / (e + 1.0f);
}

// ---------------- histogram of parents ----------------
__global__ void hist_kernel(const int* __restrict__ parent, int* __restrict__ counts, int E) {
    int e = blockIdx.x * blockDim.x + threadIdx.x;
    if (e < E) atomicAdd(&counts[parent[e]], 1);
}

// ---------------- exclusive scan (3-phase) ----------------
#define SCAN_B 1024
__global__ __launch_bounds__(SCAN_B) void scanA(const int* __restrict__ counts,
                                                int* __restrict__ off,
                                                int* __restrict__ bsum, int n) {
    __shared__ int lds[SCAN_B];
    int t = threadIdx.x;
    int i = blockIdx.x * SCAN_B + t;
    int v = (i < n - 1) ? counts[i] : 0;   // phantom last element = 0 -> off[N]=E
    lds[t] = v;
    for (int s = 1; s < SCAN_B; s <<= 1) {
        __syncthreads();
        int u = (t >= s) ? lds[t - s] : 0;
        __syncthreads();
        lds[t] += u;
    }
    __syncthreads();
    if (i < n) off[i] = lds[t] - v;              // exclusive, pre-base
    if (t == SCAN_B - 1) bsum[blockIdx.x] = lds[t];
}

// parallel exclusive scan of up to 128 block sums (nb = 98 here)
__global__ __launch_bounds__(128) void scanB(int* __restrict__ bsum, int nb) {
    __shared__ int lds[128];
    int t = threadIdx.x;
    int v = (t < nb) ? bsum[t] : 0;
    lds[t] = v;
    for (int s = 1; s < 128; s <<= 1) {
        __syncthreads();
        int u = (t >= s) ? lds[t - s] : 0;
        __syncthreads();
        lds[t] += u;
    }
    __syncthreads();
    if (t < nb) bsum[t] = lds[t] - v;            // exclusive
}

__global__ __launch_bounds__(SCAN_B) void scanC(int* __restrict__ off, const int* __restrict__ bsum,
                                                int* __restrict__ cursor, int n) {
    int i = blockIdx.x * SCAN_B + threadIdx.x;
    if (i < n) {
        int v = off[i] + bsum[blockIdx.x];
        off[i] = v;
        if (i < n - 1) cursor[i] = v;            // cursor[node] = segment start
    }
}

// ---------------- build: packed 32B CSR records {p0..p4, child, parent, pad} ----------------
#define BBLK 256
__global__ __launch_bounds__(BBLK) void build_kernel(const float* __restrict__ arc,
                                                     const float* __restrict__ W1,
                                                     const float* __restrict__ b1,
                                                     const int* __restrict__ parent,
                                                     const int* __restrict__ child,
                                                     int* __restrict__ cursor,
                                                     float4* __restrict__ rec, int E) {
    __shared__ float lds[BBLK * ARC_D];
    int t = threadIdx.x;
    int base = blockIdx.x * BBLK;
    int cnt = E - base; if (cnt > BBLK) cnt = BBLK;
    // coalesced stage of 256 rows x 17 floats
    for (int k = t; k < cnt * ARC_D; k += BBLK)
        lds[k] = arc[(size_t)base * ARC_D + k];
    __syncthreads();
    if (t < cnt) {
        int e = base + t;
        const float* row = &lds[t * ARC_D];
        float p[HID];
        #pragma unroll
        for (int j = 0; j < HID; ++j) p[j] = b1[j];
        #pragma unroll
        for (int i = 0; i < ARC_D; ++i) {
            float x = row[i];
            #pragma unroll
            for (int j = 0; j < HID; ++j) p[j] += x * W1[i * HID + j];
        }
        int pa = parent[e];
        int pos = atomicAdd(&cursor[pa], 1);
        // single aligned 32B record: 2x dwordx4 to the same 32B chunk
        rec[2 * (size_t)pos]     = make_float4(p[0], p[1], p[2], p[3]);
        rec[2 * (size_t)pos + 1] = make_float4(p[4], __uint_as_float((unsigned)child[e]),
                                               __uint_as_float((unsigned)pa), 0.0f);
    }
}

// ---------------- one fixed-point iteration: 4 lanes per node ----------------
__global__ __launch_bounds__(256) void iter_kernel(const int* __restrict__ off,
                                                   const float4* __restrict__ rec,
                                                   const float* __restrict__ W1,
                                                   const float* __restrict__ W2,
                                                   const float* __restrict__ b2,
                                                   const float* __restrict__ src,
                                                   float* __restrict__ dst) {
    int tid = blockIdx.x * blockDim.x + threadIdx.x;
    int n  = tid >> 2;          // node = 4-lane group
    int sl = tid & 3;           // sub-lane within group
    if (n >= N_NODES) return;
    // uniform-address weight loads
    float w1b[STATE][HID];
    #pragma unroll
    for (int k = 0; k < STATE; ++k)
        #pragma unroll
        for (int j = 0; j < HID; ++j) w1b[k][j] = W1[(ARC_D + k) * HID + j];
    float w2[HID][STATE];
    #pragma unroll
    for (int j = 0; j < HID; ++j)
        #pragma unroll
        for (int k = 0; k < STATE; ++k) w2[j][k] = W2[j * STATE + k];
    float b2v[STATE];
    #pragma unroll
    for (int k = 0; k < STATE; ++k) b2v[k] = b2[k];

    int s0 = off[n];
    int s1 = off[n + 1];
    float acc0 = 0.f, acc1 = 0.f, acc2 = 0.f, acc3 = 0.f;
    for (int i = s0 + sl; i < s1; i += 4) {
        float4 r0 = rec[2 * (size_t)i];
        float4 r1 = rec[2 * (size_t)i + 1];
        int c = (int)__float_as_uint(r1.y);
        float4 s = ((const float4*)src)[c];
        float p[HID] = {r0.x, r0.y, r0.z, r0.w};
        p[4] = r1.x;
        float h[HID];
        #pragma unroll
        for (int j = 0; j < HID; ++j) {
            float v = p[j] + s.x * w1b[0][j] + s.y * w1b[1][j]
                           + s.z * w1b[2][j] + s.w * w1b[3][j];
            h[j] = fast_tanh(v);
        }
        float m[STATE];
        #pragma unroll
        for (int k = 0; k < STATE; ++k) {
            float v = b2v[k];
            #pragma unroll
            for (int j = 0; j < HID; ++j) v += h[j] * w2[j][k];
            m[k] = fast_tanh(v);
        }
        acc0 += m[0]; acc1 += m[1]; acc2 += m[2]; acc3 += m[3];
    }
    // reduce across the 4-lane group
    acc0 += __shfl_xor(acc0, 1); acc0 += __shfl_xor(acc0, 2);
    acc1 += __shfl_xor(acc1, 1); acc1 += __shfl_xor(acc1, 2);
    acc2 += __shfl_xor(acc2, 1); acc2 += __shfl_xor(acc2, 2);
    acc3 += __shfl_xor(acc3, 1); acc3 += __shfl_xor(acc3, 2);
    if (sl == 0)
        ((float4*)dst)[n] = make_float4(acc0, acc1, acc2, acc3);
}

// ---------------- output MLP + softmax ----------------
__global__ __launch_bounds__(256) void out_kernel(const float* __restrict__ state,
                                                  const float* __restrict__ Wo1,
                                                  const float* __restrict__ bo1,
                                                  const float* __restrict__ Wo2,
                                                  const float* __restrict__ bo2,
                                                  float* __restrict__ out) {
    int n = blockIdx.x * blockDim.x + threadIdx.x;
    if (n >= N_NODES) return;
    float4 s = ((const float4*)state)[n];
    float ho[HID];
    #pragma unroll
    for (int j = 0; j < HID; ++j) {
        float v = bo1[j] + s.x * Wo1[0 * HID + j] + s.y * Wo1[1 * HID + j]
                         + s.z * Wo1[2 * HID + j] + s.w * Wo1[3 * HID + j];
        ho[j] = fast_tanh(v);
    }
    float lg[OUT_C];
    float mx = -1e30f;
    #pragma unroll
    for (int o = 0; o < OUT_C; ++o) {
        float v = bo2[o];
        #pragma unroll
        for (int j = 0; j < HID; ++j) v += ho[j] * Wo2[j * OUT_C + o];
        lg[o] = v; mx = fmaxf(mx, v);
    }
    float sum = 0.f;
    #pragma unroll
    for (int o = 0; o < OUT_C; ++o) { lg[o] = __expf(lg[o] - mx); sum += lg[o]; }
    float inv = 1.0f / sum;
    float4* op = (float4*)&out[(size_t)n * OUT_C];
    op[0] = make_float4(lg[0] * inv, lg[1] * inv, lg[2] * inv, lg[3] * inv);
    op[1] = make_float4(lg[4] * inv, lg[5] * inv, lg[6] * inv, lg[7] * inv);
    op[2] = make_float4(lg[8] * inv, lg[9] * inv, lg[10] * inv, lg[11] * inv);
    op[3] = make_float4(lg[12] * inv, lg[13] * inv, lg[14] * inv, lg[15] * inv);
}

extern "C" void kernel_launch(void* const* d_in, const int* in_sizes, int n_in,
                              void* d_out, int out_size, void* d_ws, size_t ws_size,
                              hipStream_t stream) {
    const float* arc   = (const float*)d_in[0];
    const float* W1    = (const float*)d_in[1];
    const float* b1    = (const float*)d_in[2];
    const float* W2    = (const float*)d_in[3];
    const float* b2    = (const float*)d_in[4];
    const float* Wo1   = (const float*)d_in[5];
    const float* bo1   = (const float*)d_in[6];
    const float* Wo2   = (const float*)d_in[7];
    const float* bo2   = (const float*)d_in[8];
    const int* parent  = (const int*)d_in[9];
    const int* child   = (const int*)d_in[10];
    float* out = (float*)d_out;

    char* ws = (char*)d_ws;
    size_t o = 0;
    auto alloc = [&](size_t bytes) { void* p = ws + o; o += (bytes + 255) & ~255ULL; return p; };
    float4* rec   = (float4*)alloc((size_t)N_EDGES * 32);       // 51.2 MB packed CSR records
    int*   counts = (int*)alloc((size_t)N_NODES * 4);
    int*   off    = (int*)alloc((size_t)(N_NODES + 1) * 4);
    int*   cursor = (int*)alloc((size_t)N_NODES * 4);
    int*   bsum   = (int*)alloc(1024 * 4);
    float* stateA = (float*)alloc((size_t)N_NODES * STATE * 4);
    float* stateB = (float*)alloc((size_t)N_NODES * STATE * 4);

    hipMemsetAsync(counts, 0, (size_t)N_NODES * 4, stream);
    hipMemsetAsync(stateA, 0, (size_t)N_NODES * STATE * 4, stream);  // state0 = zeros

    hist_kernel<<<(N_EDGES + 255) / 256, 256, 0, stream>>>(parent, counts, N_EDGES);
    int n = N_NODES + 1;
    int nb = (n + SCAN_B - 1) / SCAN_B;     // 98
    scanA<<<nb, SCAN_B, 0, stream>>>(counts, off, bsum, n);
    scanB<<<1, 128, 0, stream>>>(bsum, nb);
    scanC<<<nb, SCAN_B, 0, stream>>>(off, bsum, cursor, n);
    build_kernel<<<(N_EDGES + BBLK - 1) / BBLK, BBLK, 0, stream>>>(arc, W1, b1, parent, child,
                                                                   cursor, rec, N_EDGES);
    float* src = stateA; float* dst = stateB;
    for (int it = 0; it < MAX_IT; ++it) {
        iter_kernel<<<(N_NODES * 4 + 255) / 256, 256, 0, stream>>>(off, rec, W1, W2, b2, src, dst);
        float* tmp = src; src = dst; dst = tmp;
    }
    out_kernel<<<(N_NODES + 255) / 256, 256, 0, stream>>>(src, Wo1, bo1, Wo2, bo2, out);
}

// Round 6
// 525.781 us; speedup vs baseline: 1.5365x; 1.1526x over previous
//
#include <hip/hip_runtime.h>

#define N_NODES 100000
#define N_EDGES 1600000
#define STATE 4
#define OUT_C 16
#define HID 5
#define MAX_IT 10
#define ARC_D 17   // 1 + 2*FEAT

// branch-free tanh: 1 - 2/(exp(2x)+1); saturates to +-1, NaN-free for finite x
__device__ __forceinline__ float fast_tanh(float x) {
    float e = __expf(2.0f * x);
    return 1.0f - 2.0f / (e + 1.0f);
}

// ---------------- histogram of parents ----------------
__global__ void hist_kernel(const int* __restrict__ parent, int* __restrict__ counts, int E) {
    int e = blockIdx.x * blockDim.x + threadIdx.x;
    if (e < E) atomicAdd(&counts[parent[e]], 1);
}

// ---------------- exclusive scan (3-phase) ----------------
#define SCAN_B 1024
__global__ __launch_bounds__(SCAN_B) void scanA(const int* __restrict__ counts,
                                                int* __restrict__ off,
                                                int* __restrict__ bsum, int n) {
    __shared__ int lds[SCAN_B];
    int t = threadIdx.x;
    int i = blockIdx.x * SCAN_B + t;
    int v = (i < n - 1) ? counts[i] : 0;   // phantom last element = 0 -> off[N]=E
    lds[t] = v;
    for (int s = 1; s < SCAN_B; s <<= 1) {
        __syncthreads();
        int u = (t >= s) ? lds[t - s] : 0;
        __syncthreads();
        lds[t] += u;
    }
    __syncthreads();
    if (i < n) off[i] = lds[t] - v;              // exclusive, pre-base
    if (t == SCAN_B - 1) bsum[blockIdx.x] = lds[t];
}

// parallel exclusive scan of up to 128 block sums (nb = 98 here)
__global__ __launch_bounds__(128) void scanB(int* __restrict__ bsum, int nb) {
    __shared__ int lds[128];
    int t = threadIdx.x;
    int v = (t < nb) ? bsum[t] : 0;
    lds[t] = v;
    for (int s = 1; s < 128; s <<= 1) {
        __syncthreads();
        int u = (t >= s) ? lds[t - s] : 0;
        __syncthreads();
        lds[t] += u;
    }
    __syncthreads();
    if (t < nb) bsum[t] = lds[t] - v;            // exclusive
}

__global__ __launch_bounds__(SCAN_B) void scanC(int* __restrict__ off, const int* __restrict__ bsum,
                                                int* __restrict__ cursor, int n) {
    int i = blockIdx.x * SCAN_B + threadIdx.x;
    if (i < n) {
        int v = off[i] + bsum[blockIdx.x];
        off[i] = v;
        if (i < n - 1) cursor[i] = v;            // cursor[node] = segment start
    }
}

// ---------------- build: packed 32B CSR records {p0..p4, child, parent, pad} ----------------
#define BBLK 256
__global__ __launch_bounds__(BBLK) void build_kernel(const float* __restrict__ arc,
                                                     const float* __restrict__ W1,
                                                     const float* __restrict__ b1,
                                                     const int* __restrict__ parent,
                                                     const int* __restrict__ child,
                                                     int* __restrict__ cursor,
                                                     float4* __restrict__ rec, int E) {
    __shared__ float lds[BBLK * ARC_D];
    int t = threadIdx.x;
    int base = blockIdx.x * BBLK;
    int cnt = E - base; if (cnt > BBLK) cnt = BBLK;
    // coalesced stage of 256 rows x 17 floats
    for (int k = t; k < cnt * ARC_D; k += BBLK)
        lds[k] = arc[(size_t)base * ARC_D + k];
    __syncthreads();
    if (t < cnt) {
        int e = base + t;
        const float* row = &lds[t * ARC_D];
        float p[HID];
        #pragma unroll
        for (int j = 0; j < HID; ++j) p[j] = b1[j];
        #pragma unroll
        for (int i = 0; i < ARC_D; ++i) {
            float x = row[i];
            #pragma unroll
            for (int j = 0; j < HID; ++j) p[j] += x * W1[i * HID + j];
        }
        int pa = parent[e];
        int pos = atomicAdd(&cursor[pa], 1);
        // single aligned 32B record: 2x dwordx4 to the same 32B chunk
        rec[2 * (size_t)pos]     = make_float4(p[0], p[1], p[2], p[3]);
        rec[2 * (size_t)pos + 1] = make_float4(p[4], __uint_as_float((unsigned)child[e]),
                                               __uint_as_float((unsigned)pa), 0.0f);
    }
}

// ---------------- one fixed-point iteration: edge-parallel + wave segmented reduce ----------------
// rec is CSR-sorted by parent, so each 64-lane wave sees a few monotone parent runs.
// Segmented inclusive scan in-register; segment tails atomicAdd into dst (pre-zeroed).
__global__ __launch_bounds__(256) void iter_kernel(const float4* __restrict__ rec,
                                                   const float* __restrict__ W1,
                                                   const float* __restrict__ W2,
                                                   const float* __restrict__ b2,
                                                   const float* __restrict__ src,
                                                   float* __restrict__ dst, int E) {
    int e = blockIdx.x * blockDim.x + threadIdx.x;
    int lane = threadIdx.x & 63;
    // uniform-address weight loads
    float w1b[STATE][HID];
    #pragma unroll
    for (int k = 0; k < STATE; ++k)
        #pragma unroll
        for (int j = 0; j < HID; ++j) w1b[k][j] = W1[(ARC_D + k) * HID + j];
    float w2[HID][STATE];
    #pragma unroll
    for (int j = 0; j < HID; ++j)
        #pragma unroll
        for (int k = 0; k < STATE; ++k) w2[j][k] = W2[j * STATE + k];
    float b2v[STATE];
    #pragma unroll
    for (int k = 0; k < STATE; ++k) b2v[k] = b2[k];

    float m0 = 0.f, m1 = 0.f, m2 = 0.f, m3 = 0.f;
    int p = -1;
    if (e < E) {
        float4 r0 = rec[2 * (size_t)e];
        float4 r1 = rec[2 * (size_t)e + 1];
        int c = (int)__float_as_uint(r1.y);
        p = (int)__float_as_uint(r1.z);
        float4 s = ((const float4*)src)[c];
        float pr[HID] = {r0.x, r0.y, r0.z, r0.w};
        pr[4] = r1.x;
        float h[HID];
        #pragma unroll
        for (int j = 0; j < HID; ++j) {
            float v = pr[j] + s.x * w1b[0][j] + s.y * w1b[1][j]
                            + s.z * w1b[2][j] + s.w * w1b[3][j];
            h[j] = fast_tanh(v);
        }
        float mm[STATE];
        #pragma unroll
        for (int k = 0; k < STATE; ++k) {
            float v = b2v[k];
            #pragma unroll
            for (int j = 0; j < HID; ++j) v += h[j] * w2[j][k];
            mm[k] = fast_tanh(v);
        }
        m0 = mm[0]; m1 = mm[1]; m2 = mm[2]; m3 = mm[3];
    }
    // segmented inclusive scan over the wave, keyed on parent id
    #pragma unroll
    for (int d = 1; d < 64; d <<= 1) {
        int   pp = __shfl_up(p, d);
        float t0 = __shfl_up(m0, d);
        float t1 = __shfl_up(m1, d);
        float t2 = __shfl_up(m2, d);
        float t3 = __shfl_up(m3, d);
        bool ok = (lane >= d) && (pp == p);
        if (ok) { m0 += t0; m1 += t1; m2 += t2; m3 += t3; }
    }
    // segment tail -> one atomic flush per (segment, wave)
    int pn = __shfl_down(p, 1);
    bool tail = (lane == 63) || (pn != p);
    if (tail && e < E) {
        float* d4 = &dst[(size_t)p * STATE];
        atomicAdd(&d4[0], m0);
        atomicAdd(&d4[1], m1);
        atomicAdd(&d4[2], m2);
        atomicAdd(&d4[3], m3);
    }
}

// ---------------- output MLP + softmax ----------------
__global__ __launch_bounds__(256) void out_kernel(const float* __restrict__ state,
                                                  const float* __restrict__ Wo1,
                                                  const float* __restrict__ bo1,
                                                  const float* __restrict__ Wo2,
                                                  const float* __restrict__ bo2,
                                                  float* __restrict__ out) {
    int n = blockIdx.x * blockDim.x + threadIdx.x;
    if (n >= N_NODES) return;
    float4 s = ((const float4*)state)[n];
    float ho[HID];
    #pragma unroll
    for (int j = 0; j < HID; ++j) {
        float v = bo1[j] + s.x * Wo1[0 * HID + j] + s.y * Wo1[1 * HID + j]
                         + s.z * Wo1[2 * HID + j] + s.w * Wo1[3 * HID + j];
        ho[j] = fast_tanh(v);
    }
    float lg[OUT_C];
    float mx = -1e30f;
    #pragma unroll
    for (int o = 0; o < OUT_C; ++o) {
        float v = bo2[o];
        #pragma unroll
        for (int j = 0; j < HID; ++j) v += ho[j] * Wo2[j * OUT_C + o];
        lg[o] = v; mx = fmaxf(mx, v);
    }
    float sum = 0.f;
    #pragma unroll
    for (int o = 0; o < OUT_C; ++o) { lg[o] = __expf(lg[o] - mx); sum += lg[o]; }
    float inv = 1.0f / sum;
    float4* op = (float4*)&out[(size_t)n * OUT_C];
    op[0] = make_float4(lg[0] * inv, lg[1] * inv, lg[2] * inv, lg[3] * inv);
    op[1] = make_float4(lg[4] * inv, lg[5] * inv, lg[6] * inv, lg[7] * inv);
    op[2] = make_float4(lg[8] * inv, lg[9] * inv, lg[10] * inv, lg[11] * inv);
    op[3] = make_float4(lg[12] * inv, lg[13] * inv, lg[14] * inv, lg[15] * inv);
}

extern "C" void kernel_launch(void* const* d_in, const int* in_sizes, int n_in,
                              void* d_out, int out_size, void* d_ws, size_t ws_size,
                              hipStream_t stream) {
    const float* arc   = (const float*)d_in[0];
    const float* W1    = (const float*)d_in[1];
    const float* b1    = (const float*)d_in[2];
    const float* W2    = (const float*)d_in[3];
    const float* b2    = (const float*)d_in[4];
    const float* Wo1   = (const float*)d_in[5];
    const float* bo1   = (const float*)d_in[6];
    const float* Wo2   = (const float*)d_in[7];
    const float* bo2   = (const float*)d_in[8];
    const int* parent  = (const int*)d_in[9];
    const int* child   = (const int*)d_in[10];
    float* out = (float*)d_out;

    char* ws = (char*)d_ws;
    size_t o = 0;
    auto alloc = [&](size_t bytes) { void* p = ws + o; o += (bytes + 255) & ~255ULL; return p; };
    float4* rec   = (float4*)alloc((size_t)N_EDGES * 32);           // 51.2 MB packed CSR records
    float* states = (float*)alloc((size_t)(MAX_IT + 1) * N_NODES * STATE * 4);  // 17.6 MB, 11 buffers
    int*   counts = (int*)alloc((size_t)N_NODES * 4);
    int*   off    = (int*)alloc((size_t)(N_NODES + 1) * 4);
    int*   cursor = (int*)alloc((size_t)N_NODES * 4);
    int*   bsum   = (int*)alloc(1024 * 4);

    hipMemsetAsync(counts, 0, (size_t)N_NODES * 4, stream);
    // state[0] = zeros (init) AND state[1..10] = zeros (atomic accumulators)
    hipMemsetAsync(states, 0, (size_t)(MAX_IT + 1) * N_NODES * STATE * 4, stream);

    hist_kernel<<<(N_EDGES + 255) / 256, 256, 0, stream>>>(parent, counts, N_EDGES);
    int n = N_NODES + 1;
    int nb = (n + SCAN_B - 1) / SCAN_B;     // 98
    scanA<<<nb, SCAN_B, 0, stream>>>(counts, off, bsum, n);
    scanB<<<1, 128, 0, stream>>>(bsum, nb);
    scanC<<<nb, SCAN_B, 0, stream>>>(off, bsum, cursor, n);
    build_kernel<<<(N_EDGES + BBLK - 1) / BBLK, BBLK, 0, stream>>>(arc, W1, b1, parent, child,
                                                                   cursor, rec, N_EDGES);
    for (int it = 0; it < MAX_IT; ++it) {
        const float* src = states + (size_t)it * N_NODES * STATE;
        float* dst = states + (size_t)(it + 1) * N_NODES * STATE;
        iter_kernel<<<(N_EDGES + 255) / 256, 256, 0, stream>>>(rec, W1, W2, b2, src, dst, N_EDGES);
    }
    out_kernel<<<(N_NODES + 255) / 256, 256, 0, stream>>>(
        states + (size_t)MAX_IT * N_NODES * STATE, Wo1, bo1, Wo2, bo2, out);
}